// Round 1
// 459.658 us; speedup vs baseline: 1.0047x; 1.0047x over previous
//
#include <hip/hip_runtime.h>
#include <math.h>

typedef unsigned short u16;
typedef __attribute__((ext_vector_type(8))) short bf16x8;
typedef __attribute__((ext_vector_type(4))) float f32x4;
typedef __attribute__((ext_vector_type(2))) float f32x2;
typedef __attribute__((ext_vector_type(4))) unsigned u32x4;
typedef __attribute__((ext_vector_type(2))) unsigned u32x2;

__device__ __forceinline__ u16 f2b(float f) {
    union { float f; unsigned u; } v; v.f = f;
    unsigned r = (v.u + 0x7FFF + ((v.u >> 16) & 1)) >> 16;
    return (u16)r;
}

// unpack 2 bf16 (packed in u32) -> f32x2 {even, odd}
__device__ __forceinline__ f32x2 unpk(unsigned u) {
    union { u32x2 q; f32x2 f; } v;
    v.q.x = u << 16;
    v.q.y = u & 0xFFFF0000u;
    return v.f;
}
// hardware packed f32->bf16 (RNE), lo -> bits[15:0], hi -> bits[31:16]
__device__ __forceinline__ unsigned cvt_pk(f32x2 e) {
    unsigned r;
    asm("v_cvt_pk_bf16_f32 %0, %1, %2" : "=v"(r) : "v"(e.x), "v"(e.y));
    return r;
}
__device__ __forceinline__ f32x2 pkfma(f32x2 a, f32x2 b, f32x2 c) {
    return __builtin_elementwise_fma(a, b, c);
}

// ---- weight prep into MFMA B-fragment order ----
__global__ void prep_frag(const float* __restrict__ src, u16* __restrict__ dst,
                          int G, int KCB, int NOC, int TS) {
    int idx = blockIdx.x * 256 + threadIdx.x;
    if (idx >= KCB * G * 512) return;
    int j = idx & 7, lane = (idx >> 3) & 63, rest = idx >> 9;
    int g = rest % G, kcb = rest / G;
    int oc = g * 16 + (lane & 15);
    int c = (kcb & 1) * 32 + (lane >> 4) * 8 + j;
    int k = kcb >> 1;
    float v = (oc < NOC) ? src[((size_t)oc * 64 + c) * TS + k] : 0.f;
    dst[idx] = f2b(v);
}

// ---- NCHW fp32 -> NHWC bf16 transpose ----
template<int H, int W>
__global__ __launch_bounds__(256) void nchw2nhwc_bf16(const float* __restrict__ src,
                                                      u16* __restrict__ dst) {
    const int SEG = W / 64, HW = H * W;
    int blk = blockIdx.x;
    int b = blk / (H * SEG);
    int r = blk - b * (H * SEG);
    int h = r / SEG;
    int x0 = (r - h * SEG) * 64;
    int t = threadIdx.x;
    __shared__ float lds[64][65];
    const float* sb = src + (size_t)b * 64 * HW + (size_t)h * W + x0;
    int px = t & 63, cg = t >> 6;
#pragma unroll
    for (int i = 0; i < 16; ++i) {
        int c = cg * 16 + i;
        lds[c][px] = sb[(size_t)c * HW + px];
    }
    __syncthreads();
    u16* db = dst + ((size_t)b * HW + (size_t)h * W + x0) * 64;
    int c = t & 63, pg = t >> 6;
#pragma unroll
    for (int i = 0; i < 16; ++i) {
        int p = pg * 16 + i;
        db[(size_t)p * 64 + c] = f2b(lds[c][p]);
    }
}

// ---- bilinear 2x upsample: NCHW fp32 (192^2) -> NHWC bf16 (384^2) ----
__global__ __launch_bounds__(256) void upsample_nhwc_bf16(const float* __restrict__ src,
                                                          u16* __restrict__ dst) {
    const int Hh = 192, Wh = 192, H = 384, W = 384;
    int ox0 = blockIdx.x * 32;
    int oy  = blockIdx.y;
    int b   = blockIdx.z;
    int t = threadIdx.x;
    int iy  = oy >> 1;
    int oy2 = (oy & 1) ? min(iy + 1, Hh - 1) : max(iy - 1, 0);
    int ix0m1 = ox0 / 2 - 1;
    __shared__ float lds[2][64][19];
    const float* sb = src + (size_t)b * 64 * Hh * Wh;
    for (int idx = t; idx < 2 * 64 * 18; idx += 256) {
        int r2 = idx / (64 * 18);
        int rem = idx - r2 * (64 * 18);
        int c = rem / 18;
        int p = rem - c * 18;
        int gx = min(max(ix0m1 + p, 0), Wh - 1);
        int gy = r2 ? oy2 : iy;
        lds[r2][c][p] = sb[((size_t)c * Hh + gy) * Wh + gx];
    }
    __syncthreads();
    int c = t & 63, j = t >> 6;
    u16* db = dst + ((size_t)b * H * W + (size_t)oy * W + ox0) * 64;
#pragma unroll
    for (int ii = 0; ii < 8; ++ii) {
        int opx = j * 8 + ii;
        int ox = ox0 + opx;
        int ix = ox >> 1;
        int oxn = (ox & 1) ? min(ix + 1, Wh - 1) : max(ix - 1, 0);
        int il = ix - ix0m1;
        int ol = oxn - ix0m1;
        float cc = lds[0][c][il], cn = lds[0][c][ol];
        float nc = lds[1][c][il], nn = lds[1][c][ol];
        db[(size_t)opx * 64 + c] = f2b(0.5625f * cc + 0.1875f * (cn + nc) + 0.0625f * nn);
    }
}

// ---- conv3x3 offset conv, bf16 NHWC in, fragment weights, zero-pad ----
template<int H, int W>
__global__ __launch_bounds__(256, 4) void conv_off_rA(
    const u16*  __restrict__ srcT,
    const u16*  __restrict__ wf,
    const float* __restrict__ bias,
    float* __restrict__ dst)
{
    const int HW = H * W, SEGS = W / 16;
    int t = threadIdx.x;
    int wv = t >> 6, lane = t & 63, m16 = t & 15, quad = (t >> 4) & 3;
    int seg = blockIdx.x * 4 + wv;
    int b = seg / (H * SEGS);
    int r = seg - b * (H * SEGS);
    int h = r / SEGS;
    int x0 = (r - h * SEGS) * 16;

    const u16* sb = srcT + (size_t)b * HW * 64;
    float bz0 = bias[m16];
    float bz1 = (m16 < 11) ? bias[16 + m16] : 0.f;
    f32x4 acc[2] = {{bz0,bz0,bz0,bz0},{bz1,bz1,bz1,bz1}};

#pragma unroll
    for (int k = 0; k < 9; ++k) {
        const int ki = k / 3, kj = k % 3;
        int yy = h - 1 + ki;
        int xx = x0 + m16 - 1 + kj;
        bool ok = (yy >= 0 && yy < H && xx >= 0 && xx < W);
        int yc = min(max(yy, 0), H - 1);
        int xc = min(max(xx, 0), W - 1);
        const u16* base = sb + (size_t)(yc * W + xc) * 64 + quad * 8;
#pragma unroll
        for (int cb = 0; cb < 2; ++cb) {
            u32x4 raw = *(const u32x4*)(base + cb * 32);
            union { unsigned u[4]; bf16x8 v; } A;
#pragma unroll
            for (int q = 0; q < 4; ++q) A.u[q] = ok ? raw[q] : 0u;
            const u16* wrow = wf + (size_t)((k * 2 + cb) * 2) * 512 + lane * 8;
#pragma unroll
            for (int g = 0; g < 2; ++g) {
                bf16x8 bv = *(const bf16x8*)(wrow + g * 512);
                acc[g] = __builtin_amdgcn_mfma_f32_16x16x32_bf16(A.v, bv, acc[g], 0, 0, 0);
            }
        }
    }

    int xs = x0 + quad * 4;
    float* dbase = dst + (size_t)b * 27 * HW + (size_t)h * W + xs;
    *(f32x4*)(dbase + (size_t)m16 * HW) = acc[0];
    if (m16 < 11) *(f32x4*)(dbase + (size_t)(16 + m16) * HW) = acc[1];
}

// ---- conv1x1 residual as MFMA, bf16 NHWC in -> NHWC fp32 out ----
__global__ __launch_bounds__(256) void conv1x1_rA(
    const u16*  __restrict__ srcT,
    const u16*  __restrict__ wf,
    const float* __restrict__ rb,
    float* __restrict__ resT)
{
    const int H = 192, W = 192, HW = H * W, SEGS = W / 16;
    int t = threadIdx.x;
    int wv = t >> 6, lane = t & 63, m16 = t & 15, quad = (t >> 4) & 3;
    int seg = blockIdx.x * 4 + wv;
    int b = seg / (H * SEGS);
    int r = seg - b * (H * SEGS);
    int h = r / SEGS;
    int x0 = (r - h * SEGS) * 16;

    const u16* base = srcT + ((size_t)b * HW + (size_t)h * W + x0 + m16) * 64 + quad * 8;
    f32x4 acc[4];
#pragma unroll
    for (int g = 0; g < 4; ++g) { float bz = rb[g * 16 + m16]; acc[g] = {bz,bz,bz,bz}; }

#pragma unroll
    for (int cb = 0; cb < 2; ++cb) {
        bf16x8 A = *(const bf16x8*)(base + cb * 32);
        const u16* wrow = wf + (size_t)(cb * 4) * 512 + lane * 8;
#pragma unroll
        for (int g = 0; g < 4; ++g) {
            bf16x8 bv = *(const bf16x8*)(wrow + g * 512);
            acc[g] = __builtin_amdgcn_mfma_f32_16x16x32_bf16(A, bv, acc[g], 0, 0, 0);
        }
    }

    int xs = x0 + quad * 4;
    float* ob = resT + ((size_t)b * HW + (size_t)h * W) * 64;
#pragma unroll
    for (int g = 0; g < 4; ++g) {
        int oc = g * 16 + m16;
#pragma unroll
        for (int rg = 0; rg < 4; ++rg)
            ob[(size_t)(xs + rg) * 64 + oc] = acc[g][rg];
    }
}

// ---- deformable conv v2: packed-f32 interpolation, LDS residual staging ----
template<int H, int W, bool ADD_RES>
__global__ __launch_bounds__(256, 4) void dcn_rA(
    const u16*  __restrict__ srcT,   // B x HW x 64 bf16
    const float* __restrict__ off,   // B x 27 x H x W fp32
    const u16*  __restrict__ wf,     // [18][4][64][8]
    const float* __restrict__ bias,  // 64
    const float* __restrict__ resT,  // B x (H/2*W/2) x 64 fp32 NHWC (if ADD_RES)
    float* __restrict__ dst)         // B x 64 x H x W fp32 NCHW
{
    const int HW = H * W, SEGS = W / 16;
    int t = threadIdx.x;
    int wv = t >> 6, lane = t & 63, m16 = t & 15, quad = (t >> 4) & 3;
    int seg = blockIdx.x * 4 + wv;
    int b = seg / (H * SEGS);
    int r = seg - b * (H * SEGS);
    int h = r / SEGS;
    int x0 = (r - h * SEGS) * 16;

    const u16* sb = srcT + (size_t)b * HW * 64;
    const float* offp = off + (size_t)b * 27 * HW + (size_t)h * W + x0 + m16;

    // per-wave residual staging buffer (coalesced global -> LDS, read in epilogue)
    __shared__ float lres[4][16][65];

    // prologue: first tap's offsets
    float dyc = offp[0];
    float dxc = offp[(size_t)HW];
    float msc = offp[(size_t)18 * HW];

    // stage upsampled residual row cooperatively while offset loads are in flight
    if (ADD_RES) {
        const int Hh = H / 2, Wh = W / 2;
        int iy = h >> 1;
        int oyn = (h & 1) ? min(iy + 1, Hh - 1) : max(iy - 1, 0);
        const float* r0row = resT + ((size_t)b * Hh * Wh + (size_t)iy  * Wh) * 64 + lane;
        const float* r1row = resT + ((size_t)b * Hh * Wh + (size_t)oyn * Wh) * 64 + lane;
        int ixb = x0 >> 1;
        float a0 = r0row[(size_t)max(ixb - 1, 0) * 64];
        float a1 = r1row[(size_t)max(ixb - 1, 0) * 64];
        float b0 = r0row[(size_t)ixb * 64];
        float b1 = r1row[(size_t)ixb * 64];
#pragma unroll
        for (int m = 0; m < 8; ++m) {
            int ixn = min(ixb + m + 1, Wh - 1);
            float c0 = r0row[(size_t)ixn * 64];
            float c1 = r1row[(size_t)ixn * 64];
            lres[wv][2 * m][lane]     = 0.5625f * b0 + 0.1875f * (a0 + b1) + 0.0625f * a1;
            lres[wv][2 * m + 1][lane] = 0.5625f * b0 + 0.1875f * (c0 + b1) + 0.0625f * c1;
            a0 = b0; a1 = b1; b0 = c0; b1 = c1;
        }
    }

    f32x4 acc[4];
#pragma unroll
    for (int g = 0; g < 4; ++g) { float bz = bias[g * 16 + m16]; acc[g] = {bz,bz,bz,bz}; }

#pragma unroll
    for (int k = 0; k < 9; ++k) {
        const int ki = k / 3, kj = k % 3;
        // next tap's offsets: issue one iteration ahead
        float dyn_ = 0.f, dxn_ = 0.f, msn_ = 0.f;
        if (k < 8) {
            dyn_ = offp[(size_t)(2 * k + 2) * HW];
            dxn_ = offp[(size_t)(2 * k + 3) * HW];
            msn_ = offp[(size_t)(19 + k) * HW];
        }

        float yf = (float)(h - 1 + ki) + dyc;
        float xf = (float)(x0 + m16 - 1 + kj) + dxc;
        float y0f = floorf(yf), x0f = floorf(xf);
        int yi = (int)y0f, xi = (int)x0f;
        int y0c = min(max(yi, 0), H - 1), y1c = min(max(yi + 1, 0), H - 1);
        int x0c = min(max(xi, 0), W - 1), x1c = min(max(xi + 1, 0), W - 1);
        const u16* p00 = sb + (size_t)(y0c * W + x0c) * 64 + quad * 8;
        const u16* p01 = sb + (size_t)(y0c * W + x1c) * 64 + quad * 8;
        const u16* p10 = sb + (size_t)(y1c * W + x0c) * 64 + quad * 8;
        const u16* p11 = sb + (size_t)(y1c * W + x1c) * 64 + quad * 8;

        // issue all 8 gathers before the weight math (MLP + latency cover)
        u32x4 r00a = *(const u32x4*)p00,        r00b = *(const u32x4*)(p00 + 32);
        u32x4 r01a = *(const u32x4*)p01,        r01b = *(const u32x4*)(p01 + 32);
        u32x4 r10a = *(const u32x4*)p10,        r10b = *(const u32x4*)(p10 + 32);
        u32x4 r11a = *(const u32x4*)p11,        r11b = *(const u32x4*)(p11 + 32);

        float mm = 1.f / (1.f + __expf(-msc));
        float wy = yf - y0f, wx = xf - x0f;
        float vy0 = (yi >= 0 && yi < H) ? 1.f : 0.f;
        float vy1 = (yi + 1 >= 0 && yi + 1 < H) ? 1.f : 0.f;
        float vx0 = (xi >= 0 && xi < W) ? 1.f : 0.f;
        float vx1 = (xi + 1 >= 0 && xi + 1 < W) ? 1.f : 0.f;
        float w00 = (1.f - wy) * (1.f - wx) * vy0 * vx0 * mm;
        float w01 = (1.f - wy) * wx * vy0 * vx1 * mm;
        float w10 = wy * (1.f - wx) * vy1 * vx0 * mm;
        float w11 = wy * wx * vy1 * vx1 * mm;
        f32x2 W00 = {w00, w00}, W01 = {w01, w01}, W10 = {w10, w10}, W11 = {w11, w11};

#pragma unroll
        for (int cb = 0; cb < 2; ++cb) {
            union { unsigned u[4]; bf16x8 v; } A;
#pragma unroll
            for (int q = 0; q < 4; ++q) {
                f32x2 s = pkfma(unpk(cb ? r01b[q] : r01a[q]), W01,
                                unpk(cb ? r00b[q] : r00a[q]) * W00);
                s = pkfma(unpk(cb ? r10b[q] : r10a[q]), W10, s);
                s = pkfma(unpk(cb ? r11b[q] : r11a[q]), W11, s);
                A.u[q] = cvt_pk(s);
            }
            const u16* wrow = wf + (size_t)((k * 2 + cb) * 4) * 512 + lane * 8;
#pragma unroll
            for (int g = 0; g < 4; ++g) {
                bf16x8 bv = *(const bf16x8*)(wrow + g * 512);
                acc[g] = __builtin_amdgcn_mfma_f32_16x16x32_bf16(A.v, bv, acc[g], 0, 0, 0);
            }
        }

        if (k < 8) { dyc = dyn_; dxc = dxn_; msc = msn_; }
    }

    // epilogue: ELU (+ LDS-staged residual) + NCHW f32x4 stores
    int xs = x0 + quad * 4;
    float* dbase = dst + (size_t)b * 64 * HW + (size_t)h * W + xs;
#pragma unroll
    for (int g = 0; g < 4; ++g) {
        int oc = g * 16 + m16;
        f32x4 v = acc[g];
#pragma unroll
        for (int rg = 0; rg < 4; ++rg) {
            float val = v[rg];
            val = val > 0.f ? val : (expf(val) - 1.f);
            if (ADD_RES) val += lres[wv][quad * 4 + rg][oc];
            v[rg] = val;
        }
        *(f32x4*)(dbase + (size_t)oc * HW) = v;
    }
}

extern "C" void kernel_launch(void* const* d_in, const int* in_sizes, int n_in,
                              void* d_out, int out_size, void* d_ws, size_t ws_size,
                              hipStream_t stream) {
    const float* x   = (const float*)d_in[0];
    const float* ow1 = (const float*)d_in[1];
    const float* ob1 = (const float*)d_in[2];
    const float* w1  = (const float*)d_in[3];
    const float* b1  = (const float*)d_in[4];
    const float* ow2 = (const float*)d_in[5];
    const float* ob2 = (const float*)d_in[6];
    const float* w2  = (const float*)d_in[7];
    const float* b2  = (const float*)d_in[8];
    const float* rw  = (const float*)d_in[9];
    const float* rbv = (const float*)d_in[10];
    float* out = (float*)d_out;

    float* ws   = (float*)d_ws;
    float* off1 = ws;
    float* h1   = off1 + 1990656;
    float* r    = h1   + 4718592;
    float* off2 = r    + 4718592;
    u16* xbh    = (u16*)(off2 + 7962624);
    u16* u      = xbh + 4718592;
    u16* wfd1   = u + 18874368;
    u16* wfd2   = wfd1 + 36864;
    u16* wfo1   = wfd2 + 36864;
    u16* wfo2   = wfo1 + 18432;
    u16* wf11   = wfo2 + 18432;

    prep_frag<<<144, 256, 0, stream>>>(w1,  wfd1, 4, 18, 64, 9);
    prep_frag<<<144, 256, 0, stream>>>(w2,  wfd2, 4, 18, 64, 9);
    prep_frag<<< 72, 256, 0, stream>>>(ow1, wfo1, 2, 18, 27, 9);
    prep_frag<<< 72, 256, 0, stream>>>(ow2, wfo2, 2, 18, 27, 9);
    prep_frag<<< 16, 256, 0, stream>>>(rw,  wf11, 4,  2, 64, 1);

    nchw2nhwc_bf16<192, 192><<<2 * 192 * 3, 256, 0, stream>>>(x, xbh);
    conv_off_rA<192, 192><<<(2 * 192 * 12) / 4, 256, 0, stream>>>(xbh, wfo1, ob1, off1);
    conv1x1_rA<<<(2 * 192 * 12) / 4, 256, 0, stream>>>(xbh, wf11, rbv, r);
    dcn_rA<192, 192, false><<<(2 * 192 * 12) / 4, 256, 0, stream>>>(xbh, off1, wfd1, b1, nullptr, h1);
    upsample_nhwc_bf16<<<dim3(12, 384, 2), 256, 0, stream>>>(h1, u);
    conv_off_rA<384, 384><<<(2 * 384 * 24) / 4, 256, 0, stream>>>(u, wfo2, ob2, off2);
    dcn_rA<384, 384, true><<<(2 * 384 * 24) / 4, 256, 0, stream>>>(u, off2, wfd2, b2, r, out);
}

// Round 5
// 457.314 us; speedup vs baseline: 1.0098x; 1.0051x over previous
//
#include <hip/hip_runtime.h>
#include <math.h>

typedef unsigned short u16;
typedef __attribute__((ext_vector_type(8))) short bf16x8;
typedef __attribute__((ext_vector_type(4))) float f32x4;
typedef __attribute__((ext_vector_type(2))) float f32x2;
typedef __attribute__((ext_vector_type(4))) unsigned u32x4;
typedef __attribute__((ext_vector_type(2))) unsigned u32x2;

__device__ __forceinline__ u16 f2b(float f) {
    union { float f; unsigned u; } v; v.f = f;
    unsigned r = (v.u + 0x7FFF + ((v.u >> 16) & 1)) >> 16;
    return (u16)r;
}

// unpack 2 bf16 (packed in u32) -> f32x2 {even, odd}
__device__ __forceinline__ f32x2 unpk(unsigned u) {
    union { u32x2 q; f32x2 f; } v;
    v.q.x = u << 16;
    v.q.y = u & 0xFFFF0000u;
    return v.f;
}
// hardware packed f32->bf16 (RNE), lo -> bits[15:0], hi -> bits[31:16]
__device__ __forceinline__ unsigned cvt_pk(f32x2 e) {
    unsigned r;
    asm("v_cvt_pk_bf16_f32 %0, %1, %2" : "=v"(r) : "v"(e.x), "v"(e.y));
    return r;
}
__device__ __forceinline__ f32x2 pkfma(f32x2 a, f32x2 b, f32x2 c) {
    return __builtin_elementwise_fma(a, b, c);
}

// ---- weight prep into MFMA B-fragment order ----
__global__ void prep_frag(const float* __restrict__ src, u16* __restrict__ dst,
                          int G, int KCB, int NOC, int TS) {
    int idx = blockIdx.x * 256 + threadIdx.x;
    if (idx >= KCB * G * 512) return;
    int j = idx & 7, lane = (idx >> 3) & 63, rest = idx >> 9;
    int g = rest % G, kcb = rest / G;
    int oc = g * 16 + (lane & 15);
    int c = (kcb & 1) * 32 + (lane >> 4) * 8 + j;
    int k = kcb >> 1;
    float v = (oc < NOC) ? src[((size_t)oc * 64 + c) * TS + k] : 0.f;
    dst[idx] = f2b(v);
}

// ---- NCHW fp32 -> NHWC bf16 transpose ----
template<int H, int W>
__global__ __launch_bounds__(256) void nchw2nhwc_bf16(const float* __restrict__ src,
                                                      u16* __restrict__ dst) {
    const int SEG = W / 64, HW = H * W;
    int blk = blockIdx.x;
    int b = blk / (H * SEG);
    int r = blk - b * (H * SEG);
    int h = r / SEG;
    int x0 = (r - h * SEG) * 64;
    int t = threadIdx.x;
    __shared__ float lds[64][65];
    const float* sb = src + (size_t)b * 64 * HW + (size_t)h * W + x0;
    int px = t & 63, cg = t >> 6;
#pragma unroll
    for (int i = 0; i < 16; ++i) {
        int c = cg * 16 + i;
        lds[c][px] = sb[(size_t)c * HW + px];
    }
    __syncthreads();
    u16* db = dst + ((size_t)b * HW + (size_t)h * W + x0) * 64;
    int c = t & 63, pg = t >> 6;
#pragma unroll
    for (int i = 0; i < 16; ++i) {
        int p = pg * 16 + i;
        db[(size_t)p * 64 + c] = f2b(lds[c][p]);
    }
}

// ---- bilinear 2x upsample: NCHW fp32 (192^2) -> NHWC bf16 (384^2) ----
__global__ __launch_bounds__(256) void upsample_nhwc_bf16(const float* __restrict__ src,
                                                          u16* __restrict__ dst) {
    const int Hh = 192, Wh = 192, H = 384, W = 384;
    int ox0 = blockIdx.x * 32;
    int oy  = blockIdx.y;
    int b   = blockIdx.z;
    int t = threadIdx.x;
    int iy  = oy >> 1;
    int oy2 = (oy & 1) ? min(iy + 1, Hh - 1) : max(iy - 1, 0);
    int ix0m1 = ox0 / 2 - 1;
    __shared__ float lds[2][64][19];
    const float* sb = src + (size_t)b * 64 * Hh * Wh;
    for (int idx = t; idx < 2 * 64 * 18; idx += 256) {
        int r2 = idx / (64 * 18);
        int rem = idx - r2 * (64 * 18);
        int c = rem / 18;
        int p = rem - c * 18;
        int gx = min(max(ix0m1 + p, 0), Wh - 1);
        int gy = r2 ? oy2 : iy;
        lds[r2][c][p] = sb[((size_t)c * Hh + gy) * Wh + gx];
    }
    __syncthreads();
    int c = t & 63, j = t >> 6;
    u16* db = dst + ((size_t)b * H * W + (size_t)oy * W + ox0) * 64;
#pragma unroll
    for (int ii = 0; ii < 8; ++ii) {
        int opx = j * 8 + ii;
        int ox = ox0 + opx;
        int ix = ox >> 1;
        int oxn = (ox & 1) ? min(ix + 1, Wh - 1) : max(ix - 1, 0);
        int il = ix - ix0m1;
        int ol = oxn - ix0m1;
        float cc = lds[0][c][il], cn = lds[0][c][ol];
        float nc = lds[1][c][il], nn = lds[1][c][ol];
        db[(size_t)opx * 64 + c] = f2b(0.5625f * cc + 0.1875f * (cn + nc) + 0.0625f * nn);
    }
}

// ---- conv3x3 offset conv, bf16 NHWC in, fragment weights, zero-pad ----
template<int H, int W>
__global__ __launch_bounds__(256, 4) void conv_off_rA(
    const u16*  __restrict__ srcT,
    const u16*  __restrict__ wf,
    const float* __restrict__ bias,
    float* __restrict__ dst)
{
    const int HW = H * W, SEGS = W / 16;
    int t = threadIdx.x;
    int wv = t >> 6, lane = t & 63, m16 = t & 15, quad = (t >> 4) & 3;
    int seg = blockIdx.x * 4 + wv;
    int b = seg / (H * SEGS);
    int r = seg - b * (H * SEGS);
    int h = r / SEGS;
    int x0 = (r - h * SEGS) * 16;

    const u16* sb = srcT + (size_t)b * HW * 64;
    float bz0 = bias[m16];
    float bz1 = (m16 < 11) ? bias[16 + m16] : 0.f;
    f32x4 acc[2] = {{bz0,bz0,bz0,bz0},{bz1,bz1,bz1,bz1}};

#pragma unroll
    for (int k = 0; k < 9; ++k) {
        const int ki = k / 3, kj = k % 3;
        int yy = h - 1 + ki;
        int xx = x0 + m16 - 1 + kj;
        bool ok = (yy >= 0 && yy < H && xx >= 0 && xx < W);
        int yc = min(max(yy, 0), H - 1);
        int xc = min(max(xx, 0), W - 1);
        const u16* base = sb + (size_t)(yc * W + xc) * 64 + quad * 8;
#pragma unroll
        for (int cb = 0; cb < 2; ++cb) {
            u32x4 raw = *(const u32x4*)(base + cb * 32);
            union { unsigned u[4]; bf16x8 v; } A;
#pragma unroll
            for (int q = 0; q < 4; ++q) A.u[q] = ok ? raw[q] : 0u;
            const u16* wrow = wf + (size_t)((k * 2 + cb) * 2) * 512 + lane * 8;
#pragma unroll
            for (int g = 0; g < 2; ++g) {
                bf16x8 bv = *(const bf16x8*)(wrow + g * 512);
                acc[g] = __builtin_amdgcn_mfma_f32_16x16x32_bf16(A.v, bv, acc[g], 0, 0, 0);
            }
        }
    }

    int xs = x0 + quad * 4;
    float* dbase = dst + (size_t)b * 27 * HW + (size_t)h * W + xs;
    *(f32x4*)(dbase + (size_t)m16 * HW) = acc[0];
    if (m16 < 11) *(f32x4*)(dbase + (size_t)(16 + m16) * HW) = acc[1];
}

// ---- conv1x1 residual as MFMA, bf16 NHWC in -> NHWC fp32 out ----
__global__ __launch_bounds__(256) void conv1x1_rA(
    const u16*  __restrict__ srcT,
    const u16*  __restrict__ wf,
    const float* __restrict__ rb,
    float* __restrict__ resT)
{
    const int H = 192, W = 192, HW = H * W, SEGS = W / 16;
    int t = threadIdx.x;
    int wv = t >> 6, lane = t & 63, m16 = t & 15, quad = (t >> 4) & 3;
    int seg = blockIdx.x * 4 + wv;
    int b = seg / (H * SEGS);
    int r = seg - b * (H * SEGS);
    int h = r / SEGS;
    int x0 = (r - h * SEGS) * 16;

    const u16* base = srcT + ((size_t)b * HW + (size_t)h * W + x0 + m16) * 64 + quad * 8;
    f32x4 acc[4];
#pragma unroll
    for (int g = 0; g < 4; ++g) { float bz = rb[g * 16 + m16]; acc[g] = {bz,bz,bz,bz}; }

#pragma unroll
    for (int cb = 0; cb < 2; ++cb) {
        bf16x8 A = *(const bf16x8*)(base + cb * 32);
        const u16* wrow = wf + (size_t)(cb * 4) * 512 + lane * 8;
#pragma unroll
        for (int g = 0; g < 4; ++g) {
            bf16x8 bv = *(const bf16x8*)(wrow + g * 512);
            acc[g] = __builtin_amdgcn_mfma_f32_16x16x32_bf16(A, bv, acc[g], 0, 0, 0);
        }
    }

    int xs = x0 + quad * 4;
    float* ob = resT + ((size_t)b * HW + (size_t)h * W) * 64;
#pragma unroll
    for (int g = 0; g < 4; ++g) {
        int oc = g * 16 + m16;
#pragma unroll
        for (int rg = 0; rg < 4; ++rg)
            ob[(size_t)(xs + rg) * 64 + oc] = acc[g][rg];
    }
}

// ---- deformable conv v2: R1 datapath; TILED selects 16x4 block footprint ----
// Per-wave structure identical to the harness-verified R1 kernel: wave owns a
// 16x1 row segment (row h, cols x0..x0+15). TILED only changes which segment
// each wave gets: block = 16x4 patch (wave wv = row wv of the patch) + XCD
// swizzle. TILED=false reproduces R1's mapping bit-for-bit.
template<int H, int W, bool ADD_RES, bool TILED>
__global__ __launch_bounds__(256, 4) void dcn_rA(
    const u16*  __restrict__ srcT,   // B x HW x 64 bf16
    const float* __restrict__ off,   // B x 27 x H x W fp32
    const u16*  __restrict__ wf,     // [18][4][64][8]
    const float* __restrict__ bias,  // 64
    const float* __restrict__ resT,  // B x (H/2*W/2) x 64 fp32 NHWC (if ADD_RES)
    float* __restrict__ dst)         // B x 64 x H x W fp32 NCHW
{
    const int HW = H * W, SEGS = W / 16;
    int t = threadIdx.x;
    int wv = t >> 6, lane = t & 63, m16 = t & 15, quad = (t >> 4) & 3;

    int b, h, x0;
    if (TILED) {
        const int RG = H / 4;              // 4-row groups per image
        const int TPB = SEGS * RG;         // blocks per batch image
        int nb = 2 * TPB;                  // == gridDim.x (divisible by 8)
        int bid = blockIdx.x;
        int bsw = (bid & 7) * (nb >> 3) + (bid >> 3);
        b = bsw / TPB;
        int rem = bsw - b * TPB;
        int rg_ = rem / SEGS;
        int cs  = rem - rg_ * SEGS;
        h  = rg_ * 4 + wv;
        x0 = cs * 16;
    } else {
        int seg = blockIdx.x * 4 + wv;
        b = seg / (H * SEGS);
        int r = seg - b * (H * SEGS);
        h = r / SEGS;
        x0 = (r - h * SEGS) * 16;
    }

    const u16* sb = srcT + (size_t)b * HW * 64;
    const float* offp = off + (size_t)b * 27 * HW + (size_t)h * W + x0 + m16;

    // per-wave residual staging buffer (coalesced global -> LDS, read in epilogue)
    __shared__ float lres[4][16][65];

    // prologue: first tap's offsets
    float dyc = offp[0];
    float dxc = offp[(size_t)HW];
    float msc = offp[(size_t)18 * HW];

    // stage upsampled residual row cooperatively while offset loads are in flight
    if (ADD_RES) {
        const int Hh = H / 2, Wh = W / 2;
        int iy = h >> 1;
        int oyn = (h & 1) ? min(iy + 1, Hh - 1) : max(iy - 1, 0);
        const float* r0row = resT + ((size_t)b * Hh * Wh + (size_t)iy  * Wh) * 64 + lane;
        const float* r1row = resT + ((size_t)b * Hh * Wh + (size_t)oyn * Wh) * 64 + lane;
        int ixb = x0 >> 1;
        float a0 = r0row[(size_t)max(ixb - 1, 0) * 64];
        float a1 = r1row[(size_t)max(ixb - 1, 0) * 64];
        float b0 = r0row[(size_t)ixb * 64];
        float b1 = r1row[(size_t)ixb * 64];
#pragma unroll
        for (int m = 0; m < 8; ++m) {
            int ixn = min(ixb + m + 1, Wh - 1);
            float c0 = r0row[(size_t)ixn * 64];
            float c1 = r1row[(size_t)ixn * 64];
            lres[wv][2 * m][lane]     = 0.5625f * b0 + 0.1875f * (a0 + b1) + 0.0625f * a1;
            lres[wv][2 * m + 1][lane] = 0.5625f * b0 + 0.1875f * (c0 + b1) + 0.0625f * c1;
            a0 = b0; a1 = b1; b0 = c0; b1 = c1;
        }
    }

    f32x4 acc[4];
#pragma unroll
    for (int g = 0; g < 4; ++g) { float bz = bias[g * 16 + m16]; acc[g] = {bz,bz,bz,bz}; }

#pragma unroll
    for (int k = 0; k < 9; ++k) {
        const int ki = k / 3, kj = k % 3;
        // next tap's offsets: issue one iteration ahead
        float dyn_ = 0.f, dxn_ = 0.f, msn_ = 0.f;
        if (k < 8) {
            dyn_ = offp[(size_t)(2 * k + 2) * HW];
            dxn_ = offp[(size_t)(2 * k + 3) * HW];
            msn_ = offp[(size_t)(19 + k) * HW];
        }

        float yf = (float)(h - 1 + ki) + dyc;
        float xf = (float)(x0 + m16 - 1 + kj) + dxc;
        float y0f = floorf(yf), x0f = floorf(xf);
        int yi = (int)y0f, xi = (int)x0f;
        int y0c = min(max(yi, 0), H - 1), y1c = min(max(yi + 1, 0), H - 1);
        int x0c = min(max(xi, 0), W - 1), x1c = min(max(xi + 1, 0), W - 1);
        const u16* p00 = sb + (size_t)(y0c * W + x0c) * 64 + quad * 8;
        const u16* p01 = sb + (size_t)(y0c * W + x1c) * 64 + quad * 8;
        const u16* p10 = sb + (size_t)(y1c * W + x0c) * 64 + quad * 8;
        const u16* p11 = sb + (size_t)(y1c * W + x1c) * 64 + quad * 8;

        // issue all 8 gathers before the weight math (MLP + latency cover)
        u32x4 r00a = *(const u32x4*)p00,        r00b = *(const u32x4*)(p00 + 32);
        u32x4 r01a = *(const u32x4*)p01,        r01b = *(const u32x4*)(p01 + 32);
        u32x4 r10a = *(const u32x4*)p10,        r10b = *(const u32x4*)(p10 + 32);
        u32x4 r11a = *(const u32x4*)p11,        r11b = *(const u32x4*)(p11 + 32);

        float mm = 1.f / (1.f + __expf(-msc));
        float wy = yf - y0f, wx = xf - x0f;
        float vy0 = (yi >= 0 && yi < H) ? 1.f : 0.f;
        float vy1 = (yi + 1 >= 0 && yi + 1 < H) ? 1.f : 0.f;
        float vx0 = (xi >= 0 && xi < W) ? 1.f : 0.f;
        float vx1 = (xi + 1 >= 0 && xi + 1 < W) ? 1.f : 0.f;
        float w00 = (1.f - wy) * (1.f - wx) * vy0 * vx0 * mm;
        float w01 = (1.f - wy) * wx * vy0 * vx1 * mm;
        float w10 = wy * (1.f - wx) * vy1 * vx0 * mm;
        float w11 = wy * wx * vy1 * vx1 * mm;
        f32x2 W00 = {w00, w00}, W01 = {w01, w01}, W10 = {w10, w10}, W11 = {w11, w11};

#pragma unroll
        for (int cb2 = 0; cb2 < 2; ++cb2) {
            union { unsigned u[4]; bf16x8 v; } A;
#pragma unroll
            for (int q = 0; q < 4; ++q) {
                f32x2 s = pkfma(unpk(cb2 ? r01b[q] : r01a[q]), W01,
                                unpk(cb2 ? r00b[q] : r00a[q]) * W00);
                s = pkfma(unpk(cb2 ? r10b[q] : r10a[q]), W10, s);
                s = pkfma(unpk(cb2 ? r11b[q] : r11a[q]), W11, s);
                A.u[q] = cvt_pk(s);
            }
            const u16* wrow = wf + (size_t)((k * 2 + cb2) * 4) * 512 + lane * 8;
#pragma unroll
            for (int g = 0; g < 4; ++g) {
                bf16x8 bv = *(const bf16x8*)(wrow + g * 512);
                acc[g] = __builtin_amdgcn_mfma_f32_16x16x32_bf16(A.v, bv, acc[g], 0, 0, 0);
            }
        }

        if (k < 8) { dyc = dyn_; dxc = dxn_; msc = msn_; }
    }

    // epilogue: ELU (+ LDS-staged residual) + NCHW f32x4 stores
    int xs = x0 + quad * 4;
    float* dbase = dst + (size_t)b * 64 * HW + (size_t)h * W + xs;
#pragma unroll
    for (int g = 0; g < 4; ++g) {
        int oc = g * 16 + m16;
        f32x4 v = acc[g];
#pragma unroll
        for (int rg = 0; rg < 4; ++rg) {
            float val = v[rg];
            val = val > 0.f ? val : (__expf(val) - 1.f);
            if (ADD_RES) val += lres[wv][quad * 4 + rg][oc];
            v[rg] = val;
        }
        *(f32x4*)(dbase + (size_t)oc * HW) = v;
    }
}

extern "C" void kernel_launch(void* const* d_in, const int* in_sizes, int n_in,
                              void* d_out, int out_size, void* d_ws, size_t ws_size,
                              hipStream_t stream) {
    const float* x   = (const float*)d_in[0];
    const float* ow1 = (const float*)d_in[1];
    const float* ob1 = (const float*)d_in[2];
    const float* w1  = (const float*)d_in[3];
    const float* b1  = (const float*)d_in[4];
    const float* ow2 = (const float*)d_in[5];
    const float* ob2 = (const float*)d_in[6];
    const float* w2  = (const float*)d_in[7];
    const float* b2  = (const float*)d_in[8];
    const float* rw  = (const float*)d_in[9];
    const float* rbv = (const float*)d_in[10];
    float* out = (float*)d_out;

    float* ws   = (float*)d_ws;
    float* off1 = ws;
    float* h1   = off1 + 1990656;
    float* r    = h1   + 4718592;
    float* off2 = r    + 4718592;
    u16* xbh    = (u16*)(off2 + 7962624);
    u16* u      = xbh + 4718592;
    u16* wfd1   = u + 18874368;
    u16* wfd2   = wfd1 + 36864;
    u16* wfo1   = wfd2 + 36864;
    u16* wfo2   = wfo1 + 18432;
    u16* wf11   = wfo2 + 18432;

    prep_frag<<<144, 256, 0, stream>>>(w1,  wfd1, 4, 18, 64, 9);
    prep_frag<<<144, 256, 0, stream>>>(w2,  wfd2, 4, 18, 64, 9);
    prep_frag<<< 72, 256, 0, stream>>>(ow1, wfo1, 2, 18, 27, 9);
    prep_frag<<< 72, 256, 0, stream>>>(ow2, wfo2, 2, 18, 27, 9);
    prep_frag<<< 16, 256, 0, stream>>>(rw,  wf11, 4,  2, 64, 1);

    nchw2nhwc_bf16<192, 192><<<2 * 192 * 3, 256, 0, stream>>>(x, xbh);
    conv_off_rA<192, 192><<<(2 * 192 * 12) / 4, 256, 0, stream>>>(xbh, wfo1, ob1, off1);
    conv1x1_rA<<<(2 * 192 * 12) / 4, 256, 0, stream>>>(xbh, wf11, rbv, r);
    dcn_rA<192, 192, false, false><<<(2 * 192 * 12) / 4, 256, 0, stream>>>(xbh, off1, wfd1, b1, nullptr, h1);
    upsample_nhwc_bf16<<<dim3(12, 384, 2), 256, 0, stream>>>(h1, u);
    conv_off_rA<384, 384><<<(2 * 384 * 24) / 4, 256, 0, stream>>>(u, wfo2, ob2, off2);
    dcn_rA<384, 384, true, true><<<2 * 24 * 96, 256, 0, stream>>>(u, off2, wfd2, b2, r, out);
}